// Round 3
// baseline (429.606 us; speedup 1.0000x reference)
//
#include <hip/hip_runtime.h>
#include <stdint.h>

// Problem constants: x [B=2, S=4096, K=4096] -> M = 8192; weight [N=4096, K=4096]
#define M_DIM 8192
#define N_DIM 4096
#define K_DIM 4096

using int4v  = __attribute__((ext_vector_type(4))) int;
using int16v = __attribute__((ext_vector_type(16))) int;

// ---------------------------------------------------------------------------
// Pack kernel: int32 (widened int8 in [-127,127]) -> int8 bytes.
// One int4 (16 B) read per thread -> 4 B write. Both reads and writes are
// fully coalesced (wave: 1 KiB contiguous read, 256 B contiguous write).
// Handles x then weight in one dispatch (xq and wq contiguous in d_ws).
// ---------------------------------------------------------------------------
__global__ __launch_bounds__(256) void pack_kernel(const int4* __restrict__ sx,
                                                   const int4* __restrict__ sw,
                                                   unsigned int* __restrict__ dst,
                                                   int nx, int ntot) {
    int idx = blockIdx.x * blockDim.x + threadIdx.x;
    if (idx >= ntot) return;
    int4 v = (idx < nx) ? sx[idx] : sw[idx - nx];
    dst[idx] = (v.x & 0xff) | ((v.y & 0xff) << 8) | ((v.z & 0xff) << 16) |
               ((v.w & 0xff) << 24);
}

// ---------------------------------------------------------------------------
// Async global -> LDS copy, 16 B per lane (global_load_lds_dwordx4).
// LDS destination is wave-uniform base + lane*16 (no per-lane scatter).
// ---------------------------------------------------------------------------
__device__ __forceinline__ void async_copy16(const char* g, char* l) {
    __builtin_amdgcn_global_load_lds(
        (const __attribute__((address_space(1))) char*)g,
        (__attribute__((address_space(3))) char*)l, 16, 0, 0);
}

// ---------------------------------------------------------------------------
// i8 GEMM: 128x128 block tile, 256 threads = 4 waves in 2x2, each wave owns a
// 64x64 tile as 2x2 grid of 32x32 MFMA tiles (mfma_i32_32x32x32_i8, two
// k-steps per BK=64). LDS: A 128x64 i8 + B 128x64 i8 = 16 KiB.
// C[m,n] = sum_k x[m,k] * w[n,k]  (both operands K-major).
// A/B frag: m(or n)=lane&31, k = (lane>>5)*16 + j, j in [0,16).
// C/D frag: col = lane&31, row = (reg&3) + 8*(reg>>2) + 4*(lane>>5).
// ---------------------------------------------------------------------------
__global__ __launch_bounds__(256, 2) void gemm_i8_kernel(
    const char* __restrict__ Aq,   // [M, K] int8
    const char* __restrict__ Bq,   // [N, K] int8
    const int* __restrict__ bias,  // [N] int32 (widened int8)
    const float* __restrict__ a_ptr,
    const float* __restrict__ b_ptr,
    int32_t* __restrict__ out)     // [M, N] int32 holding int8 values
{
    __shared__ char As[128 * 64];
    __shared__ char Bs[128 * 64];

    const int tid  = threadIdx.x;
    const int lane = tid & 63;
    const int wave = tid >> 6;
    const int wr   = wave >> 1;   // wave row (0..1) -> 64-row slab
    const int wc   = wave & 1;    // wave col (0..1) -> 64-col slab
    const int m0   = blockIdx.y * 128;
    const int n0   = blockIdx.x * 128;

    const float alpha = *a_ptr;
    const float beta  = *b_ptr;

    int16v acc[2][2] = {};  // 64 accumulator regs

    // Staging: thread t fills LDS bytes [t*16, t*16+16) of each half-tile.
    // Row-major [128][64]: row = tid>>2, col = (tid&3)*16 — matches the
    // global source row/col below, so lane-contiguous LDS dst is correct.
    const int srow = tid >> 2;          // 0..63
    const int scol = (tid & 3) * 16;    // 0,16,32,48

    const char* aG0 = Aq + (size_t)(m0 + srow) * K_DIM + scol;
    const char* aG1 = aG0 + (size_t)64 * K_DIM;
    const char* bG0 = Bq + (size_t)(n0 + srow) * K_DIM + scol;
    const char* bG1 = bG0 + (size_t)64 * K_DIM;
    char* aL0 = &As[tid * 16];
    char* aL1 = &As[tid * 16 + 4096];
    char* bL0 = &Bs[tid * 16];
    char* bL1 = &Bs[tid * 16 + 4096];

    // Fragment read coordinates.
    const int fm = lane & 31;           // row within 32-tile
    const int fk = (lane >> 5) * 16;    // byte offset of this lane's k-group

    for (int k0 = 0; k0 < K_DIM; k0 += 64) {
        async_copy16(aG0 + k0, aL0);
        async_copy16(aG1 + k0, aL1);
        async_copy16(bG0 + k0, bL0);
        async_copy16(bG1 + k0, bL1);
        __syncthreads();  // drains vmcnt(0) -> LDS tiles valid

        int4v af[2][2], bf[2][2];
#pragma unroll
        for (int i = 0; i < 2; ++i)
#pragma unroll
            for (int kk = 0; kk < 2; ++kk) {
                af[i][kk] = *(const int4v*)
                    &As[(wr * 64 + i * 32 + fm) * 64 + kk * 32 + fk];
                bf[i][kk] = *(const int4v*)
                    &Bs[(wc * 64 + i * 32 + fm) * 64 + kk * 32 + fk];
            }

#pragma unroll
        for (int i = 0; i < 2; ++i)
#pragma unroll
            for (int j = 0; j < 2; ++j)
#pragma unroll
                for (int kk = 0; kk < 2; ++kk)
                    acc[i][j] = __builtin_amdgcn_mfma_i32_32x32x32_i8(
                        af[i][kk], bf[j][kk], acc[i][j], 0, 0, 0);

        __syncthreads();  // all reads done before next-iter staging overwrites
    }

    // Epilogue: col = lane&31, row = (reg&3) + 8*(reg>>2) + 4*(lane>>5).
    const int ocol  = lane & 31;
    const int rbase = (lane >> 5) * 4;
#pragma unroll
    for (int j = 0; j < 2; ++j) {
        const int gn = n0 + wc * 64 + j * 32 + ocol;
        const float bb = beta * (float)bias[gn];
#pragma unroll
        for (int i = 0; i < 2; ++i) {
            const int gm = m0 + wr * 64 + i * 32;
#pragma unroll
            for (int r = 0; r < 16; ++r) {
                const int row = (r & 3) + 8 * (r >> 2) + rbase;
                float v = alpha * (float)acc[i][j][r] + bb;
                v = rintf(v);                       // round half-to-even (numpy)
                v = fminf(fmaxf(v, -128.0f), 127.0f);
                out[(size_t)(gm + row) * N_DIM + gn] = (int32_t)v;
            }
        }
    }
}

// ---------------------------------------------------------------------------
extern "C" void kernel_launch(void* const* d_in, const int* in_sizes, int n_in,
                              void* d_out, int out_size, void* d_ws, size_t ws_size,
                              hipStream_t stream) {
    const int*   x    = (const int*)d_in[0];    // [M, K] widened int8
    const int*   w    = (const int*)d_in[1];    // [N, K] widened int8
    const int*   bias = (const int*)d_in[2];    // [N]
    const float* a    = (const float*)d_in[3];  // alpha scalar
    const float* b    = (const float*)d_in[4];  // beta scalar
    int32_t*     out  = (int32_t*)d_out;        // [M, N]

    char* xq = (char*)d_ws;                     // 32 MiB packed x
    // wq immediately follows xq -> single contiguous dst for the pack kernel
    const int nx   = (M_DIM * K_DIM) / 4;       // int4-groups in x
    const int nw   = (N_DIM * K_DIM) / 4;
    const int ntot = nx + nw;
    pack_kernel<<<(ntot + 255) / 256, 256, 0, stream>>>(
        (const int4*)x, (const int4*)w, (unsigned int*)xq, nx, ntot);

    char* wq = xq + (size_t)M_DIM * K_DIM;      // 16 MiB packed weight

    dim3 grid(N_DIM / 128, M_DIM / 128);        // 32 x 64 = 2048 blocks
    gemm_i8_kernel<<<grid, 256, 0, stream>>>(xq, wq, bias, a, b, out);
}

// Round 4
// 409.196 us; speedup vs baseline: 1.0499x; 1.0499x over previous
//
#include <hip/hip_runtime.h>
#include <stdint.h>

// Problem constants: x [B=2, S=4096, K=4096] -> M = 8192; weight [N=4096, K=4096]
#define M_DIM 8192
#define N_DIM 4096
#define K_DIM 4096

using int4v = __attribute__((ext_vector_type(4))) int;

// ---------------------------------------------------------------------------
// Pack kernel: int32 (widened int8 in [-127,127]) -> int8 bytes.
// One int4 (16 B) read per thread -> 4 B write, fully coalesced.
// x and weight packed in one dispatch (xq, wq contiguous in d_ws).
// ---------------------------------------------------------------------------
__global__ __launch_bounds__(256) void pack_kernel(const int4* __restrict__ sx,
                                                   const int4* __restrict__ sw,
                                                   unsigned int* __restrict__ dst,
                                                   int nx, int ntot) {
    int idx = blockIdx.x * blockDim.x + threadIdx.x;
    if (idx >= ntot) return;
    int4 v = (idx < nx) ? sx[idx] : sw[idx - nx];
    dst[idx] = (v.x & 0xff) | ((v.y & 0xff) << 8) | ((v.z & 0xff) << 16) |
               ((v.w & 0xff) << 24);
}

// ---------------------------------------------------------------------------
// Async global -> LDS copy, 16 B per lane (global_load_lds_dwordx4).
// LDS destination is wave-uniform base + lane*16 (no per-lane scatter).
// ---------------------------------------------------------------------------
__device__ __forceinline__ void async_copy16(const char* g, char* l) {
    __builtin_amdgcn_global_load_lds(
        (const __attribute__((address_space(1))) char*)g,
        (__attribute__((address_space(3))) char*)l, 16, 0, 0);
}

// ---------------------------------------------------------------------------
// i8 GEMM: 128x128 block tile, 256 threads = 4 waves in 2x2, each wave owns a
// 64x64 tile as 4x4 grid of 16x16 MFMA tiles (mfma_i32_16x16x64_i8, BK=64).
// DOUBLE-BUFFERED LDS, ONE barrier per K-iter: prefetch for iter k+1 is
// issued right after the barrier, so by the next barrier's forced vmcnt(0)
// drain it has had the whole ds_read+MFMA phase to complete.
// LDS: 2 x (A 8KB + B 8KB) = 32 KiB.
// C[m,n] = sum_k x[m,k] * w[n,k]  (both operands K-major).
// A/B frag: m=lane&15, k-group = lane>>4.  C/D: col=lane&15, row=(lane>>4)*4+reg.
// ---------------------------------------------------------------------------
__global__ __launch_bounds__(256, 2) void gemm_i8_kernel(
    const char* __restrict__ Aq,   // [M, K] int8
    const char* __restrict__ Bq,   // [N, K] int8
    const int* __restrict__ bias,  // [N] int32 (widened int8)
    const float* __restrict__ a_ptr,
    const float* __restrict__ b_ptr,
    int32_t* __restrict__ out)     // [M, N] int32 holding int8 values
{
    __shared__ char As[2][128 * 64];
    __shared__ char Bs[2][128 * 64];

    const int tid  = threadIdx.x;
    const int lane = tid & 63;
    const int wave = tid >> 6;
    const int wr   = wave >> 1;   // wave row (0..1) -> 64-row slab
    const int wc   = wave & 1;    // wave col (0..1) -> 64-col slab
    const int m0   = blockIdx.y * 128;
    const int n0   = blockIdx.x * 128;

    const float alpha = *a_ptr;
    const float beta  = *b_ptr;

    int4v acc[4][4] = {};  // 64 accumulator regs

    // Staging: thread t fills LDS bytes [t*16, t*16+16) of each half-tile.
    // Row-major [128][64]: row = tid>>2, col = (tid&3)*16.
    const int srow = tid >> 2;          // 0..63
    const int scol = (tid & 3) * 16;    // 0,16,32,48

    const char* aG0 = Aq + (size_t)(m0 + srow) * K_DIM + scol;
    const char* aG1 = aG0 + (size_t)64 * K_DIM;
    const char* bG0 = Bq + (size_t)(n0 + srow) * K_DIM + scol;
    const char* bG1 = bG0 + (size_t)64 * K_DIM;
    const int l0 = tid * 16;
    const int l1 = tid * 16 + 4096;

    // Fragment read coordinates: lane holds A[m = lane&15][k = (lane>>4)*16 + j]
    const int fr = lane & 15;
    const int fk = (lane >> 4) * 16;

    // Prologue: stage tile 0 into buffer 0.
    async_copy16(aG0, &As[0][l0]);
    async_copy16(aG1, &As[0][l1]);
    async_copy16(bG0, &Bs[0][l0]);
    async_copy16(bG1, &Bs[0][l1]);

    int cur = 0;
    for (int k0 = 0; k0 < K_DIM; k0 += 64) {
        // Single barrier: drains this wave's stage of buf(cur) (issued last
        // iter / prologue, had a full compute phase in flight) and guarantees
        // all waves finished reading buf(cur^1) (lgkmcnt(0) + barrier).
        __syncthreads();

        const int nxt = cur ^ 1;
        if (k0 + 64 < K_DIM) {
            async_copy16(aG0 + k0 + 64, &As[nxt][l0]);
            async_copy16(aG1 + k0 + 64, &As[nxt][l1]);
            async_copy16(bG0 + k0 + 64, &Bs[nxt][l0]);
            async_copy16(bG1 + k0 + 64, &Bs[nxt][l1]);
        }

        int4v af[4], bf[4];
#pragma unroll
        for (int i = 0; i < 4; ++i)
            af[i] = *(const int4v*)&As[cur][(wr * 64 + i * 16 + fr) * 64 + fk];
#pragma unroll
        for (int j = 0; j < 4; ++j)
            bf[j] = *(const int4v*)&Bs[cur][(wc * 64 + j * 16 + fr) * 64 + fk];

#pragma unroll
        for (int i = 0; i < 4; ++i)
#pragma unroll
            for (int j = 0; j < 4; ++j)
                acc[i][j] = __builtin_amdgcn_mfma_i32_16x16x64_i8(
                    af[i], bf[j], acc[i][j], 0, 0, 0);

        cur = nxt;
    }

    // Epilogue: C/D layout col = lane&15, row = (lane>>4)*4 + reg.
    const int orow = (lane >> 4) * 4;
    const int ocol = lane & 15;
#pragma unroll
    for (int j = 0; j < 4; ++j) {
        const int gn = n0 + wc * 64 + j * 16 + ocol;
        const float bb = beta * (float)bias[gn];
#pragma unroll
        for (int i = 0; i < 4; ++i) {
            const int gm = m0 + wr * 64 + i * 16 + orow;
#pragma unroll
            for (int r = 0; r < 4; ++r) {
                float v = alpha * (float)acc[i][j][r] + bb;
                v = rintf(v);                       // round half-to-even (numpy)
                v = fminf(fmaxf(v, -128.0f), 127.0f);
                out[(size_t)(gm + r) * N_DIM + gn] = (int32_t)v;
            }
        }
    }
}

// ---------------------------------------------------------------------------
extern "C" void kernel_launch(void* const* d_in, const int* in_sizes, int n_in,
                              void* d_out, int out_size, void* d_ws, size_t ws_size,
                              hipStream_t stream) {
    const int*   x    = (const int*)d_in[0];    // [M, K] widened int8
    const int*   w    = (const int*)d_in[1];    // [N, K] widened int8
    const int*   bias = (const int*)d_in[2];    // [N]
    const float* a    = (const float*)d_in[3];  // alpha scalar
    const float* b    = (const float*)d_in[4];  // beta scalar
    int32_t*     out  = (int32_t*)d_out;        // [M, N]

    char* xq = (char*)d_ws;                     // 32 MiB packed x
    const int nx   = (M_DIM * K_DIM) / 4;       // int4-groups in x
    const int nw   = (N_DIM * K_DIM) / 4;
    const int ntot = nx + nw;
    pack_kernel<<<(ntot + 255) / 256, 256, 0, stream>>>(
        (const int4*)x, (const int4*)w, (unsigned int*)xq, nx, ntot);

    char* wq = xq + (size_t)M_DIM * K_DIM;      // 16 MiB packed weight

    dim3 grid(N_DIM / 128, M_DIM / 128);        // 32 x 64 = 2048 blocks
    gemm_i8_kernel<<<grid, 256, 0, stream>>>(xq, wq, bias, a, b, out);
}